// Round 1
// baseline (272.350 us; speedup 1.0000x reference)
//
#include <hip/hip_runtime.h>
#include <hip/hip_bf16.h>

typedef short bf16x8 __attribute__((ext_vector_type(8)));
typedef float f32x4 __attribute__((ext_vector_type(4)));

static constexpr int M_DIM = 16384;   // batch
static constexpr int N_DIM = 4096;    // a2*b2
static constexpr int K_DIM = 1024;    // a1*b1

// round-to-nearest-even f32 -> bf16
__device__ __forceinline__ unsigned short f2bf(float f) {
  union { float f; unsigned u; } v; v.f = f;
  unsigned r = v.u + 0x7FFFu + ((v.u >> 16) & 1u);
  return (unsigned short)(r >> 16);
}

// Build w^T (N x K) in bf16.
// w[i*16+kk][j*32+l] = s[i][j] * sum_r a[r][i][j]*b[r][kk][l]
__global__ void make_wt_kernel(const float* __restrict__ a, const float* __restrict__ b,
                               const float* __restrict__ s, unsigned short* __restrict__ wT) {
  int idx = blockIdx.x * 256 + threadIdx.x;   // over N_DIM*K_DIM = 4M
  int k = idx & (K_DIM - 1);
  int n = idx >> 10;
  int i = k >> 4, kk = k & 15;
  int j = n >> 5, l = n & 31;
  float acc = 0.f;
#pragma unroll
  for (int r = 0; r < 8; ++r)
    acc += a[(r * 64 + i) * 128 + j] * b[(r * 16 + kk) * 32 + l];
  acc *= s[i * 128 + j];
  wT[idx] = f2bf(acc);
}

// x f32 -> bf16, 4 elems/thread
__global__ void cvt_x_kernel(const float* __restrict__ x, unsigned short* __restrict__ xb) {
  int i = blockIdx.x * 256 + threadIdx.x;
  float4 v = reinterpret_cast<const float4*>(x)[i];
  ushort4 o;
  o.x = f2bf(v.x); o.y = f2bf(v.y); o.z = f2bf(v.z); o.w = f2bf(v.w);
  reinterpret_cast<ushort4*>(xb)[i] = o;
}

// m97-structure bf16 GEMM: C = A(MxK) * BT(NxK)^T + bias, output f32.
// 128x128 tile, BK=32, 4 waves (2x2), each wave 64x64 = 4x4 frags of 16x16x32.
__global__ __launch_bounds__(256, 2) void gemm_bt_kernel(
    const unsigned short* __restrict__ A, const unsigned short* __restrict__ BT,
    const float* __restrict__ bias, float* __restrict__ C) {
  __shared__ unsigned short As[128 * 32];
  __shared__ unsigned short Bs[128 * 32];

  const int tid  = threadIdx.x;
  const int wave = tid >> 6;
  const int lane = tid & 63;

  // XCD-aware swizzle: nwg = 4096, divisible by 8 -> simple bijective remap
  int bid = blockIdx.x;
  bid = (bid & 7) * 512 + (bid >> 3);
  const int bm = bid >> 5;            // M/128 = 128 tiles
  const int bn = bid & 31;            // N/128 = 32 tiles
  const int brow = bm * 128;
  const int bcol = bn * 128;

  // staging: tile is 128x32 bf16 = 8KB = 8 chunks of 1KB (64 lanes x 16B)
  // chunk c: lane covers row = c*16 + lane/4, col8 = (lane%4)*8
  const int c0 = wave, c1 = wave + 4;
  const int rr = lane >> 2;
  const int cc = (lane & 3) * 8;
  const int gr0 = c0 * 16 + rr, gr1 = c1 * 16 + rr;

  const int wr = (wave >> 1) * 64;    // wave row offset in tile
  const int wc = (wave & 1) * 64;     // wave col offset
  const int frow = lane & 15;
  const int kgrp = lane >> 4;

  f32x4 acc[4][4] = {};

  const unsigned short* Abase = A + (size_t)brow * K_DIM;
  const unsigned short* Bbase = BT + (size_t)bcol * K_DIM;

  for (int k0 = 0; k0 < K_DIM; k0 += 32) {
    __builtin_amdgcn_global_load_lds(
      (__attribute__((address_space(1))) void*)(Abase + gr0 * K_DIM + k0 + cc),
      (__attribute__((address_space(3))) void*)(As + c0 * 512), 16, 0, 0);
    __builtin_amdgcn_global_load_lds(
      (__attribute__((address_space(1))) void*)(Abase + gr1 * K_DIM + k0 + cc),
      (__attribute__((address_space(3))) void*)(As + c1 * 512), 16, 0, 0);
    __builtin_amdgcn_global_load_lds(
      (__attribute__((address_space(1))) void*)(Bbase + gr0 * K_DIM + k0 + cc),
      (__attribute__((address_space(3))) void*)(Bs + c0 * 512), 16, 0, 0);
    __builtin_amdgcn_global_load_lds(
      (__attribute__((address_space(1))) void*)(Bbase + gr1 * K_DIM + k0 + cc),
      (__attribute__((address_space(3))) void*)(Bs + c1 * 512), 16, 0, 0);
    __syncthreads();   // compiler drains vmcnt before barrier

    bf16x8 af[4], bfv[4];
#pragma unroll
    for (int mi = 0; mi < 4; ++mi)
      af[mi] = *(const bf16x8*)&As[(wr + mi * 16 + frow) * 32 + kgrp * 8];
#pragma unroll
    for (int ni = 0; ni < 4; ++ni)
      bfv[ni] = *(const bf16x8*)&Bs[(wc + ni * 16 + frow) * 32 + kgrp * 8];
#pragma unroll
    for (int mi = 0; mi < 4; ++mi)
#pragma unroll
      for (int ni = 0; ni < 4; ++ni)
        acc[mi][ni] = __builtin_amdgcn_mfma_f32_16x16x32_bf16(af[mi], bfv[ni], acc[mi][ni], 0, 0, 0);
    __syncthreads();
  }

  // epilogue: C/D layout col = lane&15, row = (lane>>4)*4 + reg  [m89/m91]
  const int row0 = brow + wr + kgrp * 4;
  const int col0 = bcol + wc + frow;
#pragma unroll
  for (int ni = 0; ni < 4; ++ni) {
    const int col = col0 + ni * 16;
    const float bv = bias[col];
#pragma unroll
    for (int mi = 0; mi < 4; ++mi) {
      const int row = row0 + mi * 16;
#pragma unroll
      for (int r = 0; r < 4; ++r)
        C[(size_t)(row + r) * N_DIM + col] = acc[mi][ni][r] + bv;
    }
  }
}

extern "C" void kernel_launch(void* const* d_in, const int* in_sizes, int n_in,
                              void* d_out, int out_size, void* d_ws, size_t ws_size,
                              hipStream_t stream) {
  const float* x    = (const float*)d_in[0];
  const float* a    = (const float*)d_in[1];
  const float* b    = (const float*)d_in[2];
  const float* s    = (const float*)d_in[3];
  const float* bias = (const float*)d_in[4];
  float* out = (float*)d_out;

  unsigned short* xb = (unsigned short*)d_ws;                                   // 32 MB
  unsigned short* wT = (unsigned short*)((char*)d_ws + (size_t)M_DIM * K_DIM * 2); // + 8 MB

  cvt_x_kernel<<<(M_DIM * K_DIM / 4) / 256, 256, 0, stream>>>(x, xb);
  make_wt_kernel<<<(N_DIM * K_DIM) / 256, 256, 0, stream>>>(a, b, s, wT);
  gemm_bt_kernel<<<(M_DIM / 128) * (N_DIM / 128), 256, 0, stream>>>(xb, wT, bias, out);
}

// Round 4
// 248.896 us; speedup vs baseline: 1.0942x; 1.0942x over previous
//
#include <hip/hip_runtime.h>
#include <hip/hip_bf16.h>

typedef short bf16x8 __attribute__((ext_vector_type(8)));
typedef float f32x4 __attribute__((ext_vector_type(4)));

static constexpr int M_DIM = 16384;
static constexpr int N_DIM = 4096;
static constexpr int K_DIM = 1024;

__device__ __forceinline__ unsigned short f2bf(float f) {
  union { float f; unsigned u; } v; v.f = f;
  unsigned r = v.u + 0x7FFFu + ((v.u >> 16) & 1u);
  return (unsigned short)(r >> 16);
}

__global__ void make_wt_kernel(const float* __restrict__ a, const float* __restrict__ b,
                               const float* __restrict__ s, unsigned short* __restrict__ wT) {
  int idx = blockIdx.x * 256 + threadIdx.x;
  int k = idx & (K_DIM - 1);
  int n = idx >> 10;
  int i = k >> 4, kk = k & 15;
  int j = n >> 5, l = n & 31;
  float acc = 0.f;
#pragma unroll
  for (int r = 0; r < 8; ++r)
    acc += a[(r * 64 + i) * 128 + j] * b[(r * 16 + kk) * 32 + l];
  acc *= s[i * 128 + j];
  wT[idx] = f2bf(acc);
}

__global__ void cvt_x_kernel(const float* __restrict__ x, unsigned short* __restrict__ xb) {
  int i = blockIdx.x * 256 + threadIdx.x;
  float4 v = reinterpret_cast<const float4*>(x)[i];
  ushort4 o;
  o.x = f2bf(v.x); o.y = f2bf(v.y); o.z = f2bf(v.z); o.w = f2bf(v.w);
  reinterpret_cast<ushort4*>(xb)[i] = o;
}

// ---------------- 256x256 phase-split GEMM, drain-0 publishes ----------------
// C(M,N) = A(M,K) * BT(N,K)^T + bias ; A,BT bf16, C f32.
// 512 threads = 8 waves (2 M x 4 N). Per wave: 128x64 out = 8x4 frags 16x16.
// LDS: A,B tiles 256x64 bf16, double-buffered = 128 KiB -> 1 block/CU.
// XOR swizzle: chunk(g) of row R stored at LDS chunk g^(R&7) (pre-swizzled
// global source + swizzled ds_read; involution verified numerically).
// Publishes use vmcnt(0) ONCE per K-tile, after ph4's register-only MFMA —
// robust to spill/RA-inserted vmem ops (counted-vmcnt is not), latency mostly
// hidden (A-stages issued ph1, B-stages ph3).

#define PH_BARRIER __builtin_amdgcn_s_barrier()
#define WAITV0     do { asm volatile("s_waitcnt vmcnt(0)" ::: "memory"); \
                        __builtin_amdgcn_sched_barrier(0); } while (0)
#define WAITL      do { asm volatile("s_waitcnt lgkmcnt(0)" ::: "memory"); \
                        __builtin_amdgcn_sched_barrier(0); } while (0)

__device__ __forceinline__ void quad_mfma(f32x4 (&acc)[8][4], const bf16x8 (&aF)[4][2],
                                          const bf16x8 (&bH)[2][2], int mbase, int nbase) {
  __builtin_amdgcn_s_setprio(1);
#pragma unroll
  for (int ks = 0; ks < 2; ++ks)
#pragma unroll
    for (int mi = 0; mi < 4; ++mi)
#pragma unroll
      for (int ni = 0; ni < 2; ++ni)
        acc[mbase + mi][nbase + ni] = __builtin_amdgcn_mfma_f32_16x16x32_bf16(
            aF[mi][ks], bH[ni][ks], acc[mbase + mi][nbase + ni], 0, 0, 0);
  __builtin_amdgcn_s_setprio(0);
}

__global__ __launch_bounds__(512, 2) void gemm8_kernel(
    const unsigned short* __restrict__ A, const unsigned short* __restrict__ BT,
    const float* __restrict__ bias, float* __restrict__ C) {
  __shared__ __align__(16) unsigned short Al[2][16384];
  __shared__ __align__(16) unsigned short Bl[2][16384];

  const int tid  = threadIdx.x;
  const int lane = tid & 63;
  const int wave = tid >> 6;
  const int wm = wave >> 2;          // 0..1
  const int wn = wave & 3;           // 0..3
  const int wr = wm * 128;
  const int wc = wn * 64;
  const int frow = lane & 15;
  const int kg = lane >> 4;          // 0..3
  const int swz0 = (kg * 16) ^ ((lane & 7) << 4);         // row&7 == lane&7 (rows step by 16)
  const int swz1 = (64 + kg * 16) ^ ((lane & 7) << 4);

  // block swizzle: 4x4 groups (1024x1024 super-tiles), groups chunked per XCD
  int bid = blockIdx.x;              // 1024 blocks = 64 groups x 16
  int gid = bid >> 4, lid = bid & 15;
  gid = ((gid & 7) << 3) | (gid >> 3);          // bijective, 64 % 8 == 0
  const int bm = (gid >> 2) * 4 + (lid >> 2);   // 0..63
  const int bn = (gid & 3) * 4 + (lid & 3);     // 0..15
  const int brow = bm * 256, bcol = bn * 256;

  const unsigned short* Abase = A + (size_t)brow * K_DIM;
  const unsigned short* Bbase = BT + (size_t)bcol * K_DIM;

  // staging: quarter q = 64 rows; thread -> global row q*64 + (tid>>3),
  // pre-swizzled in-row chunk; LDS dest = uniform base + lane*16 (HW).
  const int srow = tid >> 3;
  const int scol = ((((tid & 7) << 4) ^ ((srow & 7) << 4)) >> 1);
  const int ldsu = __builtin_amdgcn_readfirstlane(wave * 512);   // shorts

#define STG(dst, base, q, k0) __builtin_amdgcn_global_load_lds( \
    (const __attribute__((address_space(1))) void*)((base) + (size_t)((q)*64 + srow) * K_DIM + (k0) + scol), \
    (__attribute__((address_space(3))) void*)((dst) + (q)*4096 + ldsu), 16, 0, 0)

#define STG4(dst, base, k0) do { STG(dst, base, 0, k0); STG(dst, base, 1, k0); \
                                 STG(dst, base, 2, k0); STG(dst, base, 3, k0); } while (0)

#define LOAD_A_HALF(P, h) { _Pragma("unroll") for (int mi = 0; mi < 4; ++mi) { \
    const char* p_ = (const char*)(P) + (wr + frow + ((h)*4 + mi) * 16) * 128; \
    aF[mi][0] = *(const bf16x8*)(p_ + swz0); aF[mi][1] = *(const bf16x8*)(p_ + swz1); } }

#define LOAD_B_HALF(P, h, dst) { _Pragma("unroll") for (int ni = 0; ni < 2; ++ni) { \
    const char* p_ = (const char*)(P) + (wc + frow + ((h)*2 + ni) * 16) * 128; \
    dst[ni][0] = *(const bf16x8*)(p_ + swz0); dst[ni][1] = *(const bf16x8*)(p_ + swz1); } }

  f32x4 acc[8][4] = {};
  bf16x8 aF[4][2], b0[2][2], b1[2][2];

  // prologue: T0 A+B (buf0) + T1 B (buf1); drain everything once.
  STG4(Bl[0], Bbase, 0);
  STG4(Al[0], Abase, 0);
  STG4(Bl[1], Bbase, 64);
  WAITV0;
  PH_BARRIER;

  // One K-tile = 4 phases. SA = 4 A-stages (other A buffer, safe anytime after
  // publish). SB = 4 B-stages (own B buffer; all B reads drained at ph2's
  // WAITL, which precedes ph2's closing barrier, which precedes ph3). Publish:
  // register-only ph4 MFMA first, then vmcnt(0) + barrier.
#define TILE4(PA, PB, SA, SB) \
  LOAD_A_HALF(PA, 0); LOAD_B_HALF(PB, 0, b0); \
  SA; \
  PH_BARRIER; WAITL; \
  quad_mfma(acc, aF, b0, 0, 0); \
  PH_BARRIER; \
  LOAD_B_HALF(PB, 1, b1); \
  PH_BARRIER; WAITL; \
  quad_mfma(acc, aF, b1, 0, 2); \
  PH_BARRIER; \
  LOAD_A_HALF(PA, 1); \
  SB; \
  PH_BARRIER; WAITL; \
  quad_mfma(acc, aF, b1, 4, 2); \
  PH_BARRIER; \
  quad_mfma(acc, aF, b0, 4, 0); \
  WAITV0; \
  PH_BARRIER;

  int k = 0;
#pragma unroll 1
  for (int i = 0; i < 7; ++i) {
    // even tile E=k (buf0): stage A(k+64)->Al[1] at ph1, B(k+128)->Bl[0] at ph3
    TILE4(Al[0], Bl[0],
      STG4(Al[1], Abase, k + 64),
      STG4(Bl[0], Bbase, k + 128));
    // odd tile O=k+64 (buf1): stage A(k+128)->Al[0], B(k+192)->Bl[1]
    TILE4(Al[1], Bl[1],
      STG4(Al[0], Abase, k + 128),
      STG4(Bl[1], Bbase, k + 192));
    k += 128;
  }
  // k = 896: T14 (buf0) stages only A15; T15 (buf1) stages nothing
  TILE4(Al[0], Bl[0], STG4(Al[1], Abase, k + 64), (void)0);
  TILE4(Al[1], Bl[1], (void)0, (void)0);

  // ---- epilogue: per-wave LDS transpose -> contiguous float4 stores ----
  __syncthreads();                              // all K-loop LDS traffic done
  float* T = (float*)&Al[0][0];                 // 8 waves * 16*68 floats = 34816 B
  float* Tw = T + wave * (16 * 68);
  const int col4 = lane & 15;
  const int rsel = lane >> 4;
  float4 bv = *(const float4*)&bias[bcol + wc + col4 * 4];

#pragma unroll
  for (int mi = 0; mi < 8; ++mi) {
#pragma unroll
    for (int ni = 0; ni < 4; ++ni)
#pragma unroll
      for (int r = 0; r < 4; ++r)
        Tw[(kg * 4 + r) * 68 + ni * 16 + frow] = acc[mi][ni][r];
    WAITL;                                      // own-wave writes visible to own-wave reads
#pragma unroll
    for (int rr = 0; rr < 4; ++rr) {
      float4 v = *(float4*)&Tw[(rr * 4 + rsel) * 68 + col4 * 4];
      v.x += bv.x; v.y += bv.y; v.z += bv.z; v.w += bv.w;
      *(float4*)&C[(size_t)(brow + wr + mi * 16 + rr * 4 + rsel) * N_DIM + bcol + wc + col4 * 4] = v;
    }
    WAITL;                                      // reads done before next mi overwrites Tw
  }
}

extern "C" void kernel_launch(void* const* d_in, const int* in_sizes, int n_in,
                              void* d_out, int out_size, void* d_ws, size_t ws_size,
                              hipStream_t stream) {
  const float* x    = (const float*)d_in[0];
  const float* a    = (const float*)d_in[1];
  const float* b    = (const float*)d_in[2];
  const float* s    = (const float*)d_in[3];
  const float* bias = (const float*)d_in[4];
  float* out = (float*)d_out;

  unsigned short* xb = (unsigned short*)d_ws;
  unsigned short* wT = (unsigned short*)((char*)d_ws + (size_t)M_DIM * K_DIM * 2);

  cvt_x_kernel<<<(M_DIM * K_DIM / 4) / 256, 256, 0, stream>>>(x, xb);
  make_wt_kernel<<<(N_DIM * K_DIM) / 256, 256, 0, stream>>>(a, b, s, wT);
  gemm8_kernel<<<(M_DIM / 256) * (N_DIM / 256), 512, 0, stream>>>(xb, wT, bias, out);
}